// Round 1
// baseline (493.282 us; speedup 1.0000x reference)
//
#include <hip/hip_runtime.h>
#include <hip/hip_bf16.h>

#define CWG    16      // centroids per scan workgroup
#define TPTS   2048    // points per LDS tile
#define CAPS   256     // candidate capacity per centroid per slice
#define CAP2   512     // total candidate capacity (2 slices)
#define RADIUS_F 0.2f
#define R2SAFE 0.0401f // prefilter; exact sqrtf test applied after

// ---------------- Kernel A: pack points + squared norms, zero counters ----
__global__ void sa_prep_kernel(const float* __restrict__ vtx,
                               float4* __restrict__ pt4,
                               int* __restrict__ cnt, int N, int nCnt) {
    int i = blockIdx.x * blockDim.x + threadIdx.x;
    int stride = gridDim.x * blockDim.x;
    for (int p = i; p < N; p += stride) {
        float x = vtx[3 * p], y = vtx[3 * p + 1], z = vtx[3 * p + 2];
        float sn = fmaf(z, z, fmaf(y, y, x * x));
        pt4[p] = make_float4(x, y, z, sn);
    }
    for (int p = i; p < nCnt; p += stride) cnt[p] = 0;
}

// ---------------- Kernel B: scan all points, collect in-radius candidates --
__global__ __launch_bounds__(256) void sa_scan_kernel(
    const float4* __restrict__ pt4, const int* __restrict__ cidx,
    unsigned long long* __restrict__ cand, int* __restrict__ cnt, int N) {
    __shared__ float4 tile[TPTS];
    __shared__ unsigned long long lists[CWG][CAPS];
    __shared__ int scnt[CWG];
    __shared__ float4 cent[CWG];

    int t = threadIdx.x;
    int group = blockIdx.x >> 1, slice = blockIdx.x & 1;

    if (t < CWG) {
        int ci = cidx[group * CWG + t];
        cent[t] = pt4[ci];
        scnt[t] = 0;
    }
    __syncthreads();

    int wave = t >> 6, lane = t & 63;
    float4 c0 = cent[wave * 4 + 0];
    float4 c1 = cent[wave * 4 + 1];
    float4 c2 = cent[wave * 4 + 2];
    float4 c3 = cent[wave * 4 + 3];

    int half = N >> 1;
    int p0 = slice * half;
    int ntiles = half / TPTS;

#define PROC(CC, JJ) do { \
        float dot = fmaf(p.z, CC.z, fmaf(p.y, CC.y, p.x * CC.x)); \
        float tt  = fmaf(-2.f, dot, CC.w) + p.w; \
        if (tt <= R2SAFE) { \
            float d = sqrtf(fabsf(tt)); \
            if (d <= RADIUS_F) { \
                int slot = atomicAdd(&scnt[JJ], 1); \
                if (slot < CAPS) \
                    lists[JJ][slot] = (((unsigned long long)__float_as_uint(d)) << 32) | (unsigned)pidx; \
            } \
        } \
    } while (0)

    for (int ti = 0; ti < ntiles; ++ti) {
        __syncthreads();
        const float4* src = pt4 + p0 + ti * TPTS;
        for (int i = t; i < TPTS; i += 256) tile[i] = src[i];
        __syncthreads();
        int pbase = p0 + ti * TPTS;
#pragma unroll 4
        for (int b = 0; b < TPTS / 64; ++b) {
            float4 p = tile[b * 64 + lane];
            int pidx = pbase + b * 64 + lane;
            PROC(c0, wave * 4 + 0);
            PROC(c1, wave * 4 + 1);
            PROC(c2, wave * 4 + 2);
            PROC(c3, wave * 4 + 3);
        }
    }
#undef PROC
    __syncthreads();

    for (int j = 0; j < CWG; ++j) {
        int n = min(scnt[j], CAPS);
        int g = group * CWG + j;
        if (t == 0) cnt[g * 2 + slice] = n;
        size_t base = ((size_t)g * 2 + slice) * CAPS;
        for (int s = t; s < n; s += 256) cand[base + s] = lists[j][s];
    }
}

// ---------------- Kernel C: select 64 nearest, MLP, masked max -------------
__global__ __launch_bounds__(256) void sa_mlp_kernel(
    const float4* __restrict__ pt4, const int* __restrict__ cidx,
    const unsigned long long* __restrict__ cand, const int* __restrict__ cnt,
    const float* __restrict__ W1, const float* __restrict__ b1,
    const float* __restrict__ W2, const float* __restrict__ b2,
    const float* __restrict__ W3, const float* __restrict__ b3,
    float* __restrict__ out) {
    __shared__ unsigned long long key_s[CAP2];
    __shared__ int sel_s[64];
    __shared__ float feat_s[64][8];
    __shared__ float h1_s[64 * 65];
    __shared__ float h2_s[64 * 65];
    __shared__ float4 cent_s;

    int t = threadIdx.x;
    int cblk = blockIdx.x;

    int n0 = min(cnt[cblk * 2 + 0], CAPS);
    int n1 = min(cnt[cblk * 2 + 1], CAPS);
    const unsigned long long* s0 = cand + ((size_t)cblk * 2 + 0) * CAPS;
    const unsigned long long* s1 = cand + ((size_t)cblk * 2 + 1) * CAPS;
    for (int s = t; s < n0; s += 256) key_s[s] = s0[s];
    for (int s = t; s < n1; s += 256) key_s[n0 + s] = s1[s];
    if (t == 0) cent_s = pt4[cidx[cblk]];
    int n = n0 + n1;
    __syncthreads();

    int nsel = min(n, 64);
    if (n > 64) {
        for (int i = t; i < n; i += 256) {
            unsigned long long ki = key_s[i];
            int rank = 0;
            for (int j = 0; j < n; ++j) rank += (key_s[j] < ki) ? 1 : 0;
            if (rank < 64) sel_s[rank] = (int)(ki & 0xffffffffu);
        }
    } else {
        for (int i = t; i < n; i += 256) sel_s[i] = (int)(key_s[i] & 0xffffffffu);
    }
    __syncthreads();

    if (t < 64) {
        if (t < nsel) {
            float4 p = pt4[sel_s[t]];
            float4 cc = cent_s;
            feat_s[t][0] = p.x;        feat_s[t][1] = p.y;        feat_s[t][2] = p.z;
            feat_s[t][3] = p.x - cc.x; feat_s[t][4] = p.y - cc.y; feat_s[t][5] = p.z - cc.z;
        } else {
            for (int i = 0; i < 6; ++i) feat_s[t][i] = 0.f;
        }
    }
    __syncthreads();

    int k = t & 63;     // candidate index owned by this lane
    int grp = t >> 6;   // wave id: channel group

    // L1: 6 -> 64
    {
        float f0 = feat_s[k][0], f1 = feat_s[k][1], f2 = feat_s[k][2];
        float f3 = feat_s[k][3], f4 = feat_s[k][4], f5 = feat_s[k][5];
#pragma unroll
        for (int q = 0; q < 16; ++q) {
            int c1 = grp * 16 + q;
            float acc = b1[c1];
            acc = fmaf(f0, W1[0 * 64 + c1], acc);
            acc = fmaf(f1, W1[1 * 64 + c1], acc);
            acc = fmaf(f2, W1[2 * 64 + c1], acc);
            acc = fmaf(f3, W1[3 * 64 + c1], acc);
            acc = fmaf(f4, W1[4 * 64 + c1], acc);
            acc = fmaf(f5, W1[5 * 64 + c1], acc);
            h1_s[k * 65 + c1] = fmaxf(acc, 0.f);
        }
    }
    __syncthreads();

    // L2: 64 -> 64
    {
        float acc[16];
#pragma unroll
        for (int q = 0; q < 16; ++q) acc[q] = b2[grp * 16 + q];
        for (int i = 0; i < 64; ++i) {
            float hv = h1_s[k * 65 + i];
            const float4* w = (const float4*)(W2 + i * 64 + grp * 16);
            float4 w0 = w[0], w1 = w[1], w2 = w[2], w3 = w[3];
            acc[0]  = fmaf(hv, w0.x, acc[0]);  acc[1]  = fmaf(hv, w0.y, acc[1]);
            acc[2]  = fmaf(hv, w0.z, acc[2]);  acc[3]  = fmaf(hv, w0.w, acc[3]);
            acc[4]  = fmaf(hv, w1.x, acc[4]);  acc[5]  = fmaf(hv, w1.y, acc[5]);
            acc[6]  = fmaf(hv, w1.z, acc[6]);  acc[7]  = fmaf(hv, w1.w, acc[7]);
            acc[8]  = fmaf(hv, w2.x, acc[8]);  acc[9]  = fmaf(hv, w2.y, acc[9]);
            acc[10] = fmaf(hv, w2.z, acc[10]); acc[11] = fmaf(hv, w2.w, acc[11]);
            acc[12] = fmaf(hv, w3.x, acc[12]); acc[13] = fmaf(hv, w3.y, acc[13]);
            acc[14] = fmaf(hv, w3.z, acc[14]); acc[15] = fmaf(hv, w3.w, acc[15]);
        }
#pragma unroll
        for (int q = 0; q < 16; ++q)
            h2_s[k * 65 + grp * 16 + q] = fmaxf(acc[q], 0.f);
    }
    __syncthreads();

    // L3: 64 -> 128, then max over k
    {
        float acc[32];
#pragma unroll
        for (int q = 0; q < 32; ++q) acc[q] = b3[grp * 32 + q];
        for (int i = 0; i < 64; ++i) {
            float hv = h2_s[k * 65 + i];
            const float4* w = (const float4*)(W3 + i * 128 + grp * 32);
#pragma unroll
            for (int q4 = 0; q4 < 8; ++q4) {
                float4 wv = w[q4];
                acc[q4 * 4 + 0] = fmaf(hv, wv.x, acc[q4 * 4 + 0]);
                acc[q4 * 4 + 1] = fmaf(hv, wv.y, acc[q4 * 4 + 1]);
                acc[q4 * 4 + 2] = fmaf(hv, wv.z, acc[q4 * 4 + 2]);
                acc[q4 * 4 + 3] = fmaf(hv, wv.w, acc[q4 * 4 + 3]);
            }
        }
        float ninf = __int_as_float(0xff800000);
        if (k >= nsel) {
#pragma unroll
            for (int q = 0; q < 32; ++q) acc[q] = ninf;
        }
#pragma unroll
        for (int q = 0; q < 32; ++q) {
            float v = acc[q];
            v = fmaxf(v, __shfl_xor(v, 1));
            v = fmaxf(v, __shfl_xor(v, 2));
            v = fmaxf(v, __shfl_xor(v, 4));
            v = fmaxf(v, __shfl_xor(v, 8));
            v = fmaxf(v, __shfl_xor(v, 16));
            v = fmaxf(v, __shfl_xor(v, 32));
            if (k == 0) out[(size_t)cblk * 128 + grp * 32 + q] = v;
        }
    }
}

extern "C" void kernel_launch(void* const* d_in, const int* in_sizes, int n_in,
                              void* d_out, int out_size, void* d_ws, size_t ws_size,
                              hipStream_t stream) {
    const float* vtx = (const float*)d_in[0];
    const int* cidx  = (const int*)d_in[1];
    const float* W1  = (const float*)d_in[2];
    const float* b1  = (const float*)d_in[3];
    const float* W2  = (const float*)d_in[4];
    const float* b2  = (const float*)d_in[5];
    const float* W3  = (const float*)d_in[6];
    const float* b3  = (const float*)d_in[7];
    float* out = (float*)d_out;

    int N = in_sizes[0] / 3;   // 65536
    int M = in_sizes[1];       // 4096

    char* ws = (char*)d_ws;
    float4* pt4 = (float4*)ws;
    unsigned long long* cand = (unsigned long long*)(ws + (size_t)N * 16);
    int* cnt = (int*)(ws + (size_t)N * 16 + (size_t)M * 2 * CAPS * 8);

    sa_prep_kernel<<<512, 256, 0, stream>>>(vtx, pt4, cnt, N, M * 2);
    sa_scan_kernel<<<(M / CWG) * 2, 256, 0, stream>>>(pt4, cidx, cand, cnt, N);
    sa_mlp_kernel<<<M, 256, 0, stream>>>(pt4, cidx, cand, cnt,
                                         W1, b1, W2, b2, W3, b3, out);
}

// Round 3
// 161.453 us; speedup vs baseline: 3.0553x; 3.0553x over previous
//
#include <hip/hip_runtime.h>
#include <hip/hip_bf16.h>

#define CWG    16
#define TPTS   2048
#define CAPS   256
#define CAP2   512
#define RADIUS_F 0.2f
#define R2SAFE 0.0401f

typedef unsigned long long ull;
typedef __attribute__((ext_vector_type(4))) _Float16 f16x4;
typedef __attribute__((ext_vector_type(8))) _Float16 f16x8;
typedef __attribute__((ext_vector_type(4))) float    f32x4;

// ---------------- Kernel A: pack points, zero counters, build f16 weights --
__global__ void sa_prep_kernel(const float* __restrict__ vtx,
                               float4* __restrict__ pt4,
                               int* __restrict__ cnt, int N, int nCnt,
                               const float* __restrict__ W1,
                               const float* __restrict__ W2,
                               const float* __restrict__ W3,
                               _Float16* __restrict__ wf16) {
    int i = blockIdx.x * blockDim.x + threadIdx.x;
    int stride = gridDim.x * blockDim.x;
    for (int p = i; p < N; p += stride) {
        float x = vtx[3 * p], y = vtx[3 * p + 1], z = vtx[3 * p + 2];
        float sn = fmaf(z, z, fmaf(y, y, x * x));
        pt4[p] = make_float4(x, y, z, sn);
    }
    for (int p = i; p < nCnt; p += stride) cnt[p] = 0;
    // W1t: [64 col][16 k] linear, k>=6 zero  (offset 0, 1024 elems)
    for (int e = i; e < 1024; e += stride) {
        int col = e >> 4, k = e & 15;
        wf16[e] = (k < 6) ? (_Float16)W1[k * 64 + col] : (_Float16)0.f;
    }
    // W2t: [64 col][64 k] XOR-swizzled  (offset 1024, 4096 elems)
    for (int e = i; e < 4096; e += stride) {
        int col = e >> 6, k = e & 63;
        wf16[1024 + col * 64 + (k ^ ((col & 7) << 3))] = (_Float16)W2[k * 64 + col];
    }
    // W3t: [128 col][64 k] XOR-swizzled (offset 5120, 8192 elems)
    for (int e = i; e < 8192; e += stride) {
        int col = e >> 6, k = e & 63;
        wf16[5120 + col * 64 + (k ^ ((col & 7) << 3))] = (_Float16)W3[k * 128 + col];
    }
}

// ---------------- Kernel B: scan all points, collect in-radius candidates --
__global__ __launch_bounds__(256) void sa_scan_kernel(
    const float4* __restrict__ pt4, const int* __restrict__ cidx,
    ull* __restrict__ cand, int* __restrict__ cnt, int N) {
    __shared__ float4 tile[TPTS];
    __shared__ ull lists[CWG][CAPS];
    __shared__ int scnt[CWG];
    __shared__ float4 cent[CWG];

    int t = threadIdx.x;
    int group = blockIdx.x >> 1, slice = blockIdx.x & 1;

    if (t < CWG) {
        int ci = cidx[group * CWG + t];
        cent[t] = pt4[ci];
        scnt[t] = 0;
    }
    __syncthreads();

    int wave = t >> 6, lane = t & 63;
    float4 c0 = cent[wave * 4 + 0];
    float4 c1 = cent[wave * 4 + 1];
    float4 c2 = cent[wave * 4 + 2];
    float4 c3 = cent[wave * 4 + 3];

    int half = N >> 1;
    int p0 = slice * half;
    int ntiles = half / TPTS;

#define PROC(CC, JJ) do { \
        float dot = fmaf(p.z, CC.z, fmaf(p.y, CC.y, p.x * CC.x)); \
        float tt  = fmaf(-2.f, dot, CC.w) + p.w; \
        if (tt <= R2SAFE) { \
            float d = sqrtf(fabsf(tt)); \
            if (d <= RADIUS_F) { \
                int slot = atomicAdd(&scnt[JJ], 1); \
                if (slot < CAPS) \
                    lists[JJ][slot] = (((ull)__float_as_uint(d)) << 32) | (unsigned)pidx; \
            } \
        } \
    } while (0)

    for (int ti = 0; ti < ntiles; ++ti) {
        __syncthreads();
        const float4* src = pt4 + p0 + ti * TPTS;
        for (int i = t; i < TPTS; i += 256) tile[i] = src[i];
        __syncthreads();
        int pbase = p0 + ti * TPTS;
#pragma unroll 4
        for (int b = 0; b < TPTS / 64; ++b) {
            float4 p = tile[b * 64 + lane];
            int pidx = pbase + b * 64 + lane;
            PROC(c0, wave * 4 + 0);
            PROC(c1, wave * 4 + 1);
            PROC(c2, wave * 4 + 2);
            PROC(c3, wave * 4 + 3);
        }
    }
#undef PROC
    __syncthreads();

    for (int j = 0; j < CWG; ++j) {
        int n = min(scnt[j], CAPS);
        int g = group * CWG + j;
        if (t == 0) cnt[g * 2 + slice] = n;
        size_t base = ((size_t)g * 2 + slice) * CAPS;
        for (int s = t; s < n; s += 256) cand[base + s] = lists[j][s];
    }
}

// ---------------- Kernel C: select 64 nearest, f16 MFMA MLP, masked max ----
__global__ __launch_bounds__(256) void sa_mlp_kernel(
    const float4* __restrict__ pt4, const int* __restrict__ cidx,
    const ull* __restrict__ cand, const int* __restrict__ cnt,
    const _Float16* __restrict__ wf16,
    const float* __restrict__ b1, const float* __restrict__ b2,
    const float* __restrict__ b3, float* __restrict__ out) {

    __shared__ __align__(16) _Float16 Wf[13312];   // w1t | w2t | w3t
    __shared__ __align__(16) float    Wb[256];     // b1 | b2 | b3
    __shared__ __align__(16) ull      wbuf[4][1024];   // keys (4KB) / h (8KB)
    __shared__ __align__(16) _Float16 featb[4][1024];  // [64 row][16 k]
    __shared__ int selb[4][64];

    int t = threadIdx.x;

    // stage weights (pre-transposed, pre-swizzled f16) + biases
    {
        const uint4* src = (const uint4*)wf16;
        uint4* dst = (uint4*)Wf;
        for (int i = t; i < 13312 / 8; i += 256) dst[i] = src[i];
        if (t < 64) Wb[t] = b1[t];
        else if (t < 128) Wb[t] = b2[t - 64];
        else Wb[t] = b3[t - 128];
    }
    __syncthreads();

    int w = t >> 6, lane = t & 63;
    int c = blockIdx.x * 4 + w;

    // ---- selection: top-64 nearest among in-radius candidates (wave-local)
    ull* key = wbuf[w];
    int n0 = min(cnt[c * 2 + 0], CAPS);
    int n1 = min(cnt[c * 2 + 1], CAPS);
    const ull* s0 = cand + ((size_t)c * 2 + 0) * CAPS;
    const ull* s1 = cand + ((size_t)c * 2 + 1) * CAPS;
    for (int i = lane; i < n0; i += 64) key[i] = s0[i];
    for (int i = lane; i < n1; i += 64) key[n0 + i] = s1[i];
    int n = n0 + n1;
    int nsel = min(n, 64);

    if (n > 64) {
        for (int i = lane; i < n; i += 64) {
            ull ki = key[i];
            int r = 0;
            for (int j = 0; j < n; ++j) r += (key[j] < ki) ? 1 : 0;
            if (r < 64) selb[w][r] = (int)(unsigned)(ki & 0xffffffffu);
        }
    } else {
        for (int i = lane; i < n; i += 64)
            selb[w][i] = (int)(unsigned)(key[i] & 0xffffffffu);
    }

    // ---- gather features -> f16 LDS [64][16] (K padded 6->16)
    {
        float4 cc = pt4[cidx[c]];
        _Float16 z = (_Float16)0.f;
        f16x8 lo = {z, z, z, z, z, z, z, z};
        if (lane < nsel) {
            float4 p = pt4[selb[w][lane]];
            lo[0] = (_Float16)p.x; lo[1] = (_Float16)p.y; lo[2] = (_Float16)p.z;
            lo[3] = (_Float16)(p.x - cc.x);
            lo[4] = (_Float16)(p.y - cc.y);
            lo[5] = (_Float16)(p.z - cc.z);
        }
        f16x8 hi = {z, z, z, z, z, z, z, z};
        *(f16x8*)&featb[w][lane * 16 + 0] = lo;
        *(f16x8*)&featb[w][lane * 16 + 8] = hi;
    }

    int r16 = lane & 15, g = lane >> 4;
    _Float16* h = (_Float16*)wbuf[w];
    const _Float16* w1 = Wf;
    const _Float16* w2 = Wf + 1024;
    const _Float16* w3 = Wf + 5120;

    // ---- L1: feat[64x16(6)] @ W1[16x64] -> relu -> h [64][64] swizzled
    {
        f16x4 a1[4];
#pragma unroll
        for (int m = 0; m < 4; ++m)
            a1[m] = *(const f16x4*)&featb[w][(m * 16 + r16) * 16 + g * 4];
#pragma unroll
        for (int nn = 0; nn < 4; ++nn) {
            int col = nn * 16 + r16;
            f16x4 b = *(const f16x4*)&w1[col * 16 + g * 4];
            float bb = Wb[col];
#pragma unroll
            for (int m = 0; m < 4; ++m) {
                f32x4 acc = {bb, bb, bb, bb};
                acc = __builtin_amdgcn_mfma_f32_16x16x16f16(a1[m], b, acc, 0, 0, 0);
#pragma unroll
                for (int reg = 0; reg < 4; ++reg) {
                    int row = m * 16 + g * 4 + reg;
                    h[row * 64 + (col ^ ((row & 7) << 3))] =
                        (_Float16)fmaxf(acc[reg], 0.f);
                }
            }
        }
    }

    // ---- L2: h[64x64] @ W2[64x64] -> relu -> h (in place; A preloaded)
    {
        f16x8 a2[4][2];
#pragma unroll
        for (int m = 0; m < 4; ++m)
#pragma unroll
            for (int kt = 0; kt < 2; ++kt) {
                int row = m * 16 + r16;
                int k0 = kt * 32 + g * 8;
                a2[m][kt] = *(const f16x8*)&h[row * 64 + (k0 ^ ((row & 7) << 3))];
            }
#pragma unroll
        for (int nn = 0; nn < 4; ++nn) {
            int col = nn * 16 + r16;
            int k0 = g * 8;
            f16x8 bA = *(const f16x8*)&w2[col * 64 + (k0 ^ ((col & 7) << 3))];
            f16x8 bB = *(const f16x8*)&w2[col * 64 + ((32 + k0) ^ ((col & 7) << 3))];
            float bb = Wb[64 + col];
#pragma unroll
            for (int m = 0; m < 4; ++m) {
                f32x4 acc = {bb, bb, bb, bb};
                acc = __builtin_amdgcn_mfma_f32_16x16x32_f16(a2[m][0], bA, acc, 0, 0, 0);
                acc = __builtin_amdgcn_mfma_f32_16x16x32_f16(a2[m][1], bB, acc, 0, 0, 0);
#pragma unroll
                for (int reg = 0; reg < 4; ++reg) {
                    int row = m * 16 + g * 4 + reg;
                    h[row * 64 + (col ^ ((row & 7) << 3))] =
                        (_Float16)fmaxf(acc[reg], 0.f);
                }
            }
        }
    }

    // ---- L3: h[64x64] @ W3[64x128] + mask + max over rows
    {
        f16x8 a3[4][2];
#pragma unroll
        for (int m = 0; m < 4; ++m)
#pragma unroll
            for (int kt = 0; kt < 2; ++kt) {
                int row = m * 16 + r16;
                int k0 = kt * 32 + g * 8;
                a3[m][kt] = *(const f16x8*)&h[row * 64 + (k0 ^ ((row & 7) << 3))];
            }
        float ninf = __int_as_float(0xff800000);
#pragma unroll
        for (int nn = 0; nn < 8; ++nn) {
            int col = nn * 16 + r16;
            int k0 = g * 8;
            f16x8 bA = *(const f16x8*)&w3[col * 64 + (k0 ^ ((col & 7) << 3))];
            f16x8 bB = *(const f16x8*)&w3[col * 64 + ((32 + k0) ^ ((col & 7) << 3))];
            float bb = Wb[128 + col];
            float vm = ninf;
#pragma unroll
            for (int m = 0; m < 4; ++m) {
                f32x4 acc = {bb, bb, bb, bb};
                acc = __builtin_amdgcn_mfma_f32_16x16x32_f16(a3[m][0], bA, acc, 0, 0, 0);
                acc = __builtin_amdgcn_mfma_f32_16x16x32_f16(a3[m][1], bB, acc, 0, 0, 0);
#pragma unroll
                for (int reg = 0; reg < 4; ++reg) {
                    int row = m * 16 + g * 4 + reg;
                    if (row < nsel) vm = fmaxf(vm, acc[reg]);
                }
            }
            vm = fmaxf(vm, __shfl_xor(vm, 16));
            vm = fmaxf(vm, __shfl_xor(vm, 32));
            if (lane < 16) out[(size_t)c * 128 + nn * 16 + lane] = vm;
        }
    }
}

extern "C" void kernel_launch(void* const* d_in, const int* in_sizes, int n_in,
                              void* d_out, int out_size, void* d_ws, size_t ws_size,
                              hipStream_t stream) {
    const float* vtx = (const float*)d_in[0];
    const int* cidx  = (const int*)d_in[1];
    const float* W1  = (const float*)d_in[2];
    const float* b1  = (const float*)d_in[3];
    const float* W2  = (const float*)d_in[4];
    const float* b2  = (const float*)d_in[5];
    const float* W3  = (const float*)d_in[6];
    const float* b3  = (const float*)d_in[7];
    float* out = (float*)d_out;

    int N = in_sizes[0] / 3;   // 65536
    int M = in_sizes[1];       // 4096

    char* ws = (char*)d_ws;
    float4* pt4 = (float4*)ws;
    ull* cand = (ull*)(ws + (size_t)N * 16);
    int* cnt = (int*)(ws + (size_t)N * 16 + (size_t)M * 2 * CAPS * 8);
    _Float16* wf16 = (_Float16*)(ws + (size_t)N * 16 + (size_t)M * 2 * CAPS * 8
                                 + (size_t)M * 2 * 4);

    sa_prep_kernel<<<512, 256, 0, stream>>>(vtx, pt4, cnt, N, M * 2,
                                            W1, W2, W3, wf16);
    sa_scan_kernel<<<(M / CWG) * 2, 256, 0, stream>>>(pt4, cidx, cand, cnt, N);
    sa_mlp_kernel<<<M / 4, 256, 0, stream>>>(pt4, cidx, cand, cnt, wf16,
                                             b1, b2, b3, out);
}

// Round 4
// 86.286 us; speedup vs baseline: 5.7168x; 1.8711x over previous
//
#include <hip/hip_runtime.h>
#include <hip/hip_bf16.h>

#define GD     50          // grid cells per dim
#define NC     (GD*GD*GD)  // 125000
#define GORG   5.0f        // grid covers [-5,5]
#define GINV   5.0f        // 1/cellsize = 1/0.2
#define CAPK   256         // in-radius candidate capacity per centroid
#define RADIUS_F 0.2f
#define R2SAFE 0.0401f

typedef unsigned long long ull;
typedef __attribute__((ext_vector_type(4))) _Float16 f16x4;
typedef __attribute__((ext_vector_type(8))) _Float16 f16x8;
typedef __attribute__((ext_vector_type(4))) float    f32x4;

__device__ __forceinline__ int cellcoord(float v) {
    int c = (int)floorf((v + GORG) * GINV);
    return min(max(c, 0), GD - 1);
}

// -------- K1: pack pt4, cell ids, cell counts, f16 weights ----------------
__global__ void sa_prep_kernel(const float* __restrict__ vtx,
                               float4* __restrict__ pt4,
                               int* __restrict__ cid,
                               int* __restrict__ cellCnt,
                               int N,
                               const float* __restrict__ W1,
                               const float* __restrict__ W2,
                               const float* __restrict__ W3,
                               _Float16* __restrict__ wf16) {
    int i = blockIdx.x * blockDim.x + threadIdx.x;
    int stride = gridDim.x * blockDim.x;
    for (int p = i; p < N; p += stride) {
        float x = vtx[3 * p], y = vtx[3 * p + 1], z = vtx[3 * p + 2];
        float sn = fmaf(z, z, fmaf(y, y, x * x));
        pt4[p] = make_float4(x, y, z, sn);
        int cc = (cellcoord(z) * GD + cellcoord(y)) * GD + cellcoord(x);
        cid[p] = cc;
        atomicAdd(&cellCnt[cc], 1);
    }
    // W1t: [64 col][16 k], k>=6 zero (offset 0)
    for (int e = i; e < 1024; e += stride) {
        int col = e >> 4, k = e & 15;
        wf16[e] = (k < 6) ? (_Float16)W1[k * 64 + col] : (_Float16)0.f;
    }
    // W2t: [64 col][64 k] XOR-swizzled (offset 1024)
    for (int e = i; e < 4096; e += stride) {
        int col = e >> 6, k = e & 63;
        wf16[1024 + col * 64 + (k ^ ((col & 7) << 3))] = (_Float16)W2[k * 64 + col];
    }
    // W3t: [128 col][64 k] XOR-swizzled (offset 5120)
    for (int e = i; e < 8192; e += stride) {
        int col = e >> 6, k = e & 63;
        wf16[5120 + col * 64 + (k ^ ((col & 7) << 3))] = (_Float16)W3[k * 128 + col];
    }
}

// -------- K2: CSR offsets via block scan + one atomic base per block ------
__global__ __launch_bounds__(256) void sa_offsets_kernel(
    const int* __restrict__ cellCnt, int* __restrict__ cellStart,
    int* __restrict__ cellCur, int* __restrict__ cursor) {
    __shared__ int sc[256];
    __shared__ int base_s;
    int t = threadIdx.x;
    int i = blockIdx.x * 256 + t;
    int c = (i < NC) ? cellCnt[i] : 0;
    sc[t] = c;
    __syncthreads();
    for (int d = 1; d < 256; d <<= 1) {
        int o = (t >= d) ? sc[t - d] : 0;
        __syncthreads();
        sc[t] += o;
        __syncthreads();
    }
    if (t == 255) base_s = atomicAdd(cursor, sc[255]);
    __syncthreads();
    int start = base_s + sc[t] - c;   // exclusive prefix + block base
    if (i < NC) { cellStart[i] = start; cellCur[i] = start; }
}

// -------- K3: scatter points into cell-sorted order -----------------------
__global__ void sa_scatter_kernel(const float4* __restrict__ pt4,
                                  const int* __restrict__ cid,
                                  int* __restrict__ cellCur,
                                  float4* __restrict__ sorted4,
                                  int* __restrict__ sidx, int N) {
    int p = blockIdx.x * blockDim.x + threadIdx.x;
    if (p < N) {
        int pos = atomicAdd(&cellCur[cid[p]], 1);
        sorted4[pos] = pt4[p];
        sidx[pos] = p;
    }
}

// -------- K4: fused neighbor-collect + top-64 + f16 MFMA MLP + max --------
__global__ __launch_bounds__(256) void sa_fused_kernel(
    const float4* __restrict__ pt4, const int* __restrict__ cidx,
    const float4* __restrict__ sorted4, const int* __restrict__ sidx,
    const int* __restrict__ cellCnt, const int* __restrict__ cellStart,
    const _Float16* __restrict__ wf16,
    const float* __restrict__ b1, const float* __restrict__ b2,
    const float* __restrict__ b3, float* __restrict__ out) {

    __shared__ __align__(16) _Float16 Wf[13312];
    __shared__ __align__(16) float    Wb[256];
    __shared__ __align__(16) ull      wbuf[4][1024];   // keys (<=2KB) then h (8KB)
    __shared__ __align__(16) _Float16 featb[4][1024];
    __shared__ int selb[4][64];
    __shared__ int pre_s[4][32];
    __shared__ int starts_s[4][28];
    __shared__ int scnt_s[4];

    int t = threadIdx.x;

    // stage weights + biases
    {
        const uint4* src = (const uint4*)wf16;
        uint4* dst = (uint4*)Wf;
        for (int i = t; i < 13312 / 8; i += 256) dst[i] = src[i];
        if (t < 64) Wb[t] = b1[t];
        else if (t < 128) Wb[t] = b2[t - 64];
        else Wb[t] = b3[t - 128];
    }
    __syncthreads();

    int w = t >> 6, lane = t & 63;
    int c = blockIdx.x * 4 + w;
    float4 cc = pt4[cidx[c]];

    // ---- neighbor cells (dedup'd 3^3 block, clamped) ----
    int cx = cellcoord(cc.x), cy = cellcoord(cc.y), cz = cellcoord(cc.z);
    int x0 = max(cx - 1, 0), x1 = min(cx + 1, GD - 1), lx = x1 - x0 + 1;
    int y0 = max(cy - 1, 0), y1 = min(cy + 1, GD - 1), ly = y1 - y0 + 1;
    int z0 = max(cz - 1, 0), z1 = min(cz + 1, GD - 1), lz = z1 - z0 + 1;
    int L = lx * ly * lz;

    int cellc = 0;
    if (lane < L) {
        int lxy = lx * ly;
        int iz = lane / lxy, rem = lane - iz * lxy;
        int iy = rem / lx, ix = rem - iy * lx;
        int cell = ((z0 + iz) * GD + (y0 + iy)) * GD + (x0 + ix);
        cellc = cellCnt[cell];
        starts_s[w][lane] = cellStart[cell];
    }
    // wave inclusive prefix of counts
    int pfx = cellc;
#pragma unroll
    for (int d = 1; d < 32; d <<= 1) {
        int o = __shfl_up(pfx, d);
        if (lane >= d) pfx += o;
    }
    if (lane < L) pre_s[w][lane + 1] = pfx;
    if (lane == 0) { pre_s[w][0] = 0; scnt_s[w] = 0; }
    int T = __shfl(pfx, L - 1);

    // ---- stream candidates, faithful distance test, append in-radius ----
    ull* key = wbuf[w];
    for (int base = 0; base < T; base += 64) {
        int s = base + lane;
        if (s < T) {
            int lo = 0, hi = L - 1;
#pragma unroll 5
            for (int it = 0; it < 5; ++it) {
                int mid = (lo + hi + 1) >> 1;
                if (lo < hi) { if (pre_s[w][mid] <= s) lo = mid; else hi = mid - 1; }
            }
            int sp = starts_s[w][lo] + (s - pre_s[w][lo]);
            float4 p = sorted4[sp];
            int pid = sidx[sp];
            float dot = fmaf(p.z, cc.z, fmaf(p.y, cc.y, p.x * cc.x));
            float tt = fmaf(-2.f, dot, cc.w) + p.w;
            if (tt <= R2SAFE) {
                float d = sqrtf(fabsf(tt));
                if (d <= RADIUS_F) {
                    int slot = atomicAdd(&scnt_s[w], 1);
                    if (slot < CAPK)
                        key[slot] = (((ull)__float_as_uint(d)) << 32) | (unsigned)pid;
                }
            }
        }
    }

    // ---- top-64 selection (rank by (d,idx) key) ----
    int n = min(scnt_s[w], CAPK);
    int nsel = min(n, 64);
    if (n > 64) {
        for (int i = lane; i < n; i += 64) {
            ull ki = key[i];
            int r = 0;
            for (int j = 0; j < n; ++j) r += (key[j] < ki) ? 1 : 0;
            if (r < 64) selb[w][r] = (int)(unsigned)(ki & 0xffffffffu);
        }
    } else {
        for (int i = lane; i < n; i += 64)
            selb[w][i] = (int)(unsigned)(key[i] & 0xffffffffu);
    }

    // ---- gather features -> f16 LDS [64][16] ----
    {
        _Float16 z = (_Float16)0.f;
        f16x8 lo8 = {z, z, z, z, z, z, z, z};
        if (lane < nsel) {
            float4 p = pt4[selb[w][lane]];
            lo8[0] = (_Float16)p.x; lo8[1] = (_Float16)p.y; lo8[2] = (_Float16)p.z;
            lo8[3] = (_Float16)(p.x - cc.x);
            lo8[4] = (_Float16)(p.y - cc.y);
            lo8[5] = (_Float16)(p.z - cc.z);
        }
        f16x8 hi8 = {z, z, z, z, z, z, z, z};
        *(f16x8*)&featb[w][lane * 16 + 0] = lo8;
        *(f16x8*)&featb[w][lane * 16 + 8] = hi8;
    }

    int r16 = lane & 15, g = lane >> 4;
    _Float16* h = (_Float16*)wbuf[w];
    const _Float16* w1 = Wf;
    const _Float16* w2 = Wf + 1024;
    const _Float16* w3 = Wf + 5120;

    // ---- L1: feat[64x16(6)] @ W1 -> relu -> h swizzled ----
    {
        f16x4 a1[4];
#pragma unroll
        for (int m = 0; m < 4; ++m)
            a1[m] = *(const f16x4*)&featb[w][(m * 16 + r16) * 16 + g * 4];
#pragma unroll
        for (int nn = 0; nn < 4; ++nn) {
            int col = nn * 16 + r16;
            f16x4 b = *(const f16x4*)&w1[col * 16 + g * 4];
            float bb = Wb[col];
#pragma unroll
            for (int m = 0; m < 4; ++m) {
                f32x4 acc = {bb, bb, bb, bb};
                acc = __builtin_amdgcn_mfma_f32_16x16x16f16(a1[m], b, acc, 0, 0, 0);
#pragma unroll
                for (int reg = 0; reg < 4; ++reg) {
                    int row = m * 16 + g * 4 + reg;
                    h[row * 64 + (col ^ ((row & 7) << 3))] =
                        (_Float16)fmaxf(acc[reg], 0.f);
                }
            }
        }
    }

    // ---- L2: h @ W2 -> relu -> h (A preloaded) ----
    {
        f16x8 a2[4][2];
#pragma unroll
        for (int m = 0; m < 4; ++m)
#pragma unroll
            for (int kt = 0; kt < 2; ++kt) {
                int row = m * 16 + r16;
                int k0 = kt * 32 + g * 8;
                a2[m][kt] = *(const f16x8*)&h[row * 64 + (k0 ^ ((row & 7) << 3))];
            }
#pragma unroll
        for (int nn = 0; nn < 4; ++nn) {
            int col = nn * 16 + r16;
            int k0 = g * 8;
            f16x8 bA = *(const f16x8*)&w2[col * 64 + (k0 ^ ((col & 7) << 3))];
            f16x8 bB = *(const f16x8*)&w2[col * 64 + ((32 + k0) ^ ((col & 7) << 3))];
            float bb = Wb[64 + col];
#pragma unroll
            for (int m = 0; m < 4; ++m) {
                f32x4 acc = {bb, bb, bb, bb};
                acc = __builtin_amdgcn_mfma_f32_16x16x32_f16(a2[m][0], bA, acc, 0, 0, 0);
                acc = __builtin_amdgcn_mfma_f32_16x16x32_f16(a2[m][1], bB, acc, 0, 0, 0);
#pragma unroll
                for (int reg = 0; reg < 4; ++reg) {
                    int row = m * 16 + g * 4 + reg;
                    h[row * 64 + (col ^ ((row & 7) << 3))] =
                        (_Float16)fmaxf(acc[reg], 0.f);
                }
            }
        }
    }

    // ---- L3: h @ W3 + mask + max over rows ----
    {
        f16x8 a3[4][2];
#pragma unroll
        for (int m = 0; m < 4; ++m)
#pragma unroll
            for (int kt = 0; kt < 2; ++kt) {
                int row = m * 16 + r16;
                int k0 = kt * 32 + g * 8;
                a3[m][kt] = *(const f16x8*)&h[row * 64 + (k0 ^ ((row & 7) << 3))];
            }
        float ninf = __int_as_float(0xff800000);
#pragma unroll
        for (int nn = 0; nn < 8; ++nn) {
            int col = nn * 16 + r16;
            int k0 = g * 8;
            f16x8 bA = *(const f16x8*)&w3[col * 64 + (k0 ^ ((col & 7) << 3))];
            f16x8 bB = *(const f16x8*)&w3[col * 64 + ((32 + k0) ^ ((col & 7) << 3))];
            float bb = Wb[128 + col];
            float vm = ninf;
#pragma unroll
            for (int m = 0; m < 4; ++m) {
                f32x4 acc = {bb, bb, bb, bb};
                acc = __builtin_amdgcn_mfma_f32_16x16x32_f16(a3[m][0], bA, acc, 0, 0, 0);
                acc = __builtin_amdgcn_mfma_f32_16x16x32_f16(a3[m][1], bB, acc, 0, 0, 0);
#pragma unroll
                for (int reg = 0; reg < 4; ++reg) {
                    int row = m * 16 + g * 4 + reg;
                    if (row < nsel) vm = fmaxf(vm, acc[reg]);
                }
            }
            vm = fmaxf(vm, __shfl_xor(vm, 16));
            vm = fmaxf(vm, __shfl_xor(vm, 32));
            if (lane < 16) out[(size_t)c * 128 + nn * 16 + lane] = vm;
        }
    }
}

extern "C" void kernel_launch(void* const* d_in, const int* in_sizes, int n_in,
                              void* d_out, int out_size, void* d_ws, size_t ws_size,
                              hipStream_t stream) {
    const float* vtx = (const float*)d_in[0];
    const int* cidx  = (const int*)d_in[1];
    const float* W1  = (const float*)d_in[2];
    const float* b1  = (const float*)d_in[3];
    const float* W2  = (const float*)d_in[4];
    const float* b2  = (const float*)d_in[5];
    const float* W3  = (const float*)d_in[6];
    const float* b3  = (const float*)d_in[7];
    float* out = (float*)d_out;

    int N = in_sizes[0] / 3;   // 65536
    int M = in_sizes[1];       // 4096

    char* ws = (char*)d_ws;
    size_t off = 0;
    float4* pt4     = (float4*)(ws + off); off += (size_t)N * 16;
    float4* sorted4 = (float4*)(ws + off); off += (size_t)N * 16;
    int* sidx       = (int*)(ws + off);    off += (size_t)N * 4;
    int* cid        = (int*)(ws + off);    off += (size_t)N * 4;
    int* cellCnt    = (int*)(ws + off);    off += (size_t)NC * 4;
    int* cursor     = (int*)(ws + off);    off += 16;
    int* cellStart  = (int*)(ws + off);    off += (size_t)NC * 4;
    int* cellCur    = (int*)(ws + off);    off += (size_t)NC * 4;
    _Float16* wf16  = (_Float16*)(ws + off);

    hipMemsetAsync(cellCnt, 0, (size_t)NC * 4 + 16, stream);  // counts + cursor
    sa_prep_kernel<<<512, 256, 0, stream>>>(vtx, pt4, cid, cellCnt, N,
                                            W1, W2, W3, wf16);
    sa_offsets_kernel<<<(NC + 255) / 256, 256, 0, stream>>>(cellCnt, cellStart,
                                                            cellCur, cursor);
    sa_scatter_kernel<<<(N + 255) / 256, 256, 0, stream>>>(pt4, cid, cellCur,
                                                           sorted4, sidx, N);
    sa_fused_kernel<<<M / 4, 256, 0, stream>>>(pt4, cidx, sorted4, sidx,
                                               cellCnt, cellStart, wf16,
                                               b1, b2, b3, out);
}